// Round 11
// baseline (1198.286 us; speedup 1.0000x reference)
//
#include <hip/hip_runtime.h>

// Match numpy's rounding exactly: no FMA contraction, same op order as reference.
#pragma clang fp contract(off)

#define B_    4
#define NT_   256
#define NZ_   192
#define NX_   192
#define NREC_ 128
#define DT_   0.001f
#define DH_   10.0f

#define N_CELL  (NZ_ * NX_)        // 36864
#define N_FIELD (B_ * N_CELL)      // 147456

#define K_     4                   // timesteps fused per launch
#define ROWS   3                   // rows owned per block
#define NTHR   1024                // threads per block (16 waves = 4/SIMD)
#define VH     (2 * K_ - 1)        // 7  vel halo rows each side
#define SH     (2 * K_)            // 8  stress halo rows each side
#define VROWS  (ROWS + 2 * VH)     // 17
#define SROWS  (ROWS + 2 * SH)     // 19
#define TILES  (NZ_ / ROWS)        // 64
#define NBLK   (B_ * TILES)        // 256  (one per CU)
#define NX4    (NX_ / 4)           // 48 float4 per row
#define LDS_BYTES ((2 * VROWS + 3 * SROWS) * NX_ * 4)   // 69888

using f4 = __attribute__((ext_vector_type(4))) float;

__device__ __forceinline__ int imax_(int a, int b) { return a > b ? a : b; }
__device__ __forceinline__ int imin_(int a, int b) { return a < b ? a : b; }

// ---------------- material precompute ----------------
__global__ void mat_kernel(const float* __restrict__ vp, const float* __restrict__ vs,
                           const float* __restrict__ rho,
                           float* __restrict__ lam, float* __restrict__ dtmu,
                           float* __restrict__ lam2mu, float* __restrict__ buoy) {
    int i = blockIdx.x * blockDim.x + threadIdx.x;
    if (i >= N_CELL) return;
    float vpi = vp[i], vsi = vs[i], rhoi = rho[i];
    float vs2 = vsi * vsi;
    float mui = rhoi * vs2;
    float lami = rhoi * (vpi * vpi - 2.0f * vs2);
    lam[i] = lami;
    dtmu[i] = DT_ * mui;             // reference: DT * mu * (...) == (DT*mu) * (...)
    lam2mu[i] = lami + 2.0f * mui;
    buoy[i] = DT_ / rhoi;
}

// One fused substep, float4-vectorized. All LDS traffic is ds_read_b128/ds_write_b128;
// x+-1 shifts are register selects. Per-element arithmetic/order identical to reference.
template<int S>
__device__ __forceinline__ void substep(
    int tid, int z0, int base, int zv0, int zs0, int sz, int sx, int b, int t0,
    float* __restrict__ vxl, float* __restrict__ vzl,
    float* __restrict__ txxl, float* __restrict__ tzzl, float* __restrict__ txzl,
    const float* __restrict__ lam, const float* __restrict__ dtmu,
    const float* __restrict__ l2m, const float* __restrict__ buoy,
    const float* __restrict__ wav,
    bool rec_ok, int rec_idx, float* __restrict__ out,
    float* __restrict__ vxw, float* __restrict__ vzw,
    float* __restrict__ txxw, float* __restrict__ tzzw, float* __restrict__ txzw) {
    const int t = t0 + S;

    // ---- velocity update on rows [z0-hv, z0+ROWS-1+hv] (in-place in LDS) ----
    {
        constexpr int hv = 2 * (K_ - 1 - S) + 1;
        const int zlo = imax_(0, z0 - hv);
        const int zhi = imin_(NZ_ - 1, z0 + ROWS - 1 + hv);
        const int n4  = (zhi - zlo + 1) * NX4;   // <= 17*48 = 816 < NTHR
        if (tid < n4) {
            int dz = tid / NX4;
            int x4 = tid - dz * NX4;
            int z  = zlo + dz;
            int x0 = x4 * 4;
            int zsrow = (z - zs0) * NX_;   // z-zs0 >= 2S+1 >= 1, <= SROWS-2
            int zvrow = (z - zv0) * NX_;
            const f4* txxR = reinterpret_cast<const f4*>(txxl + zsrow);
            const f4* txzR = reinterpret_cast<const f4*>(txzl + zsrow);
            const f4* txzM = reinterpret_cast<const f4*>(txzl + zsrow - NX_);
            const f4* tzzR = reinterpret_cast<const f4*>(tzzl + zsrow);
            const f4* tzzP = reinterpret_cast<const f4*>(tzzl + zsrow + NX_);
            f4 txo  = txxR[x4];
            f4 txn  = txxR[x4 < NX4 - 1 ? x4 + 1 : x4];   // x+1 source (clamped; unused at x=191)
            f4 tzo  = txzR[x4];
            f4 tzp  = txzR[x4 > 0 ? x4 - 1 : x4];          // x-1 source (clamped; unused at x=0)
            f4 tzm  = txzM[x4];
            f4 tzzo = tzzR[x4];
            f4 tzzp = tzzP[x4];
            f4 vxo  = reinterpret_cast<const f4*>(vxl + zvrow)[x4];
            f4 vzo  = reinterpret_cast<const f4*>(vzl + zvrow)[x4];
            f4 bu   = *reinterpret_cast<const f4*>(buoy + z * NX_ + x0);
            f4 nvx, nvz;
#pragma unroll
            for (int e = 0; e < 4; ++e) {
                int xg = x0 + e;
                float txx_c = txo[e];
                float txxp1 = (e == 3) ? txn[0] : txo[e + 1];
                float txz_c = tzo[e];
                float txzm1 = (e == 0) ? tzp[3] : tzo[e - 1];
                float dxf_txx = (xg < NX_ - 1) ? (txxp1 - txx_c) / DH_ : 0.0f;
                float dzb_txz = (z >= 1)       ? (txz_c - tzm[e]) / DH_ : 0.0f;
                float dxb_txz = (xg >= 1)      ? (txz_c - txzm1) / DH_ : 0.0f;
                float dzf_tzz = (z < NZ_ - 1)  ? (tzzp[e] - tzzo[e]) / DH_ : 0.0f;
                nvx[e] = vxo[e] + bu[e] * (dxf_txx + dzb_txz);
                nvz[e] = vzo[e] + bu[e] * (dxb_txz + dzf_tzz);
            }
            reinterpret_cast<f4*>(vxl + zvrow)[x4] = nvx;
            reinterpret_cast<f4*>(vzl + zvrow)[x4] = nvz;
            if (S == K_ - 1) {
                if (z >= z0 && z < z0 + ROWS) {
                    *reinterpret_cast<f4*>(vxw + base + z * NX_ + x0) = nvx;
                    *reinterpret_cast<f4*>(vzw + base + z * NX_ + x0) = nvz;
                }
            }
        }
    }
    __syncthreads();

    // ---- receiver recording (post-velocity snapshot), owner tile only ----
    // out layout: (NT, NREC, 2B) — out[t, r, b]=vx, out[t, r, B+b]=vz
    if (rec_ok) {
        size_t o = ((size_t)t * NREC_ + tid) * (2 * B_);
        out[o + b]      = vxl[rec_idx];
        out[o + B_ + b] = vzl[rec_idx];
    }

    // ---- stress update on rows [z0-hs, z0+ROWS-1+hs] (in-place in LDS) ----
    {
        constexpr int hs = 2 * (K_ - 1 - S);
        const int zlo = imax_(0, z0 - hs);
        const int zhi = imin_(NZ_ - 1, z0 + ROWS - 1 + hs);
        const int n4  = (zhi - zlo + 1) * NX4;   // <= 15*48 = 720 < NTHR
        if (tid < n4) {
            int dz = tid / NX4;
            int x4 = tid - dz * NX4;
            int z  = zlo + dz;
            int x0 = x4 * 4;
            int zsrow = (z - zs0) * NX_;
            int zvrow = (z - zv0) * NX_;   // z-zv0 >= 2S+1 >= 1, <= VROWS-2
            const f4* vxR = reinterpret_cast<const f4*>(vxl + zvrow);
            const f4* vxP = reinterpret_cast<const f4*>(vxl + zvrow + NX_);
            const f4* vzR = reinterpret_cast<const f4*>(vzl + zvrow);
            const f4* vzM = reinterpret_cast<const f4*>(vzl + zvrow - NX_);
            f4 vxo  = vxR[x4];
            f4 vxp  = vxR[x4 > 0 ? x4 - 1 : x4];           // x-1 source (clamped; unused at x=0)
            f4 vxzp = vxP[x4];
            f4 vzo  = vzR[x4];
            f4 vzn  = vzR[x4 < NX4 - 1 ? x4 + 1 : x4];     // x+1 source (clamped; unused at x=191)
            f4 vzm  = vzM[x4];
            f4 txxo = reinterpret_cast<const f4*>(txxl + zsrow)[x4];
            f4 tzzo = reinterpret_cast<const f4*>(tzzl + zsrow)[x4];
            f4 txzo = reinterpret_cast<const f4*>(txzl + zsrow)[x4];
            int c0 = z * NX_ + x0;
            f4 l   = *reinterpret_cast<const f4*>(lam  + c0);
            f4 lm  = *reinterpret_cast<const f4*>(l2m  + c0);
            f4 dtm = *reinterpret_cast<const f4*>(dtmu + c0);
            float w = wav[b * NT_ + t];
            f4 ntxx, ntzz, ntxz;
#pragma unroll
            for (int e = 0; e < 4; ++e) {
                int xg = x0 + e;
                float vx_c = vxo[e];
                float vz_c = vzo[e];
                float vxm1 = (e == 0) ? vxp[3] : vxo[e - 1];
                float vzp1 = (e == 3) ? vzn[0] : vzo[e + 1];
                float dvxdx  = (xg >= 1)      ? (vx_c - vxm1) / DH_ : 0.0f;
                float dvzdz  = (z >= 1)       ? (vz_c - vzm[e]) / DH_ : 0.0f;
                float dzf_vx = (z < NZ_ - 1)  ? (vxzp[e] - vx_c) / DH_ : 0.0f;
                float dxf_vz = (xg < NX_ - 1) ? (vzp1 - vz_c) / DH_ : 0.0f;
                float a  = txxo[e] + DT_ * (lm[e] * dvxdx + l[e] * dvzdz);
                float bb = tzzo[e] + DT_ * (l[e] * dvxdx + lm[e] * dvzdz);
                float cc = txzo[e] + dtm[e] * (dzf_vx + dxf_vz);
                // source injection wherever the recompute range covers it (bit-identical
                // across owner and halo-recomputing blocks)
                if (z == sz && xg == sx) { a = a + w; bb = bb + w; }
                ntxx[e] = a; ntzz[e] = bb; ntxz[e] = cc;
            }
            reinterpret_cast<f4*>(txxl + zsrow)[x4] = ntxx;
            reinterpret_cast<f4*>(tzzl + zsrow)[x4] = ntzz;
            reinterpret_cast<f4*>(txzl + zsrow)[x4] = ntxz;
            if (S == K_ - 1) {   // computed range == owned range at last substep
                *reinterpret_cast<f4*>(txxw + base + c0) = ntxx;
                *reinterpret_cast<f4*>(tzzw + base + c0) = ntzz;
                *reinterpret_cast<f4*>(txzw + base + c0) = ntxz;
            }
        }
    }
    __syncthreads();
}

// ---------------- K_ fused timesteps with trapezoidal halo recompute ----------------
__global__ void __launch_bounds__(NTHR, 4)
step_kernel(const float* __restrict__ vxr, const float* __restrict__ vzr,
            const float* __restrict__ txxr, const float* __restrict__ tzzr,
            const float* __restrict__ txzr,
            float* __restrict__ vxw, float* __restrict__ vzw,
            float* __restrict__ txxw, float* __restrict__ tzzw, float* __restrict__ txzw,
            const float* __restrict__ lam, const float* __restrict__ dtmu,
            const float* __restrict__ l2m, const float* __restrict__ buoy,
            const float* __restrict__ wav, int t0,
            const int* __restrict__ src_loc, const int* __restrict__ rec_loc,
            float* __restrict__ out) {
    extern __shared__ float smem[];
    float* __restrict__ vxl  = smem;                          // [VROWS][NX_]
    float* __restrict__ vzl  = vxl  + VROWS * NX_;
    float* __restrict__ txxl = vzl  + VROWS * NX_;            // [SROWS][NX_]
    float* __restrict__ tzzl = txxl + SROWS * NX_;
    float* __restrict__ txzl = tzzl + SROWS * NX_;

    const int tid  = threadIdx.x;
    const int b    = blockIdx.x / TILES;
    const int tile = blockIdx.x % TILES;
    const int z0   = tile * ROWS;
    const int base = b * N_CELL;
    const int zv0  = z0 - VH;       // absolute z of vel LDS row 0
    const int zs0  = z0 - SH;       // absolute z of stress LDS row 0

    const int sz = src_loc[2 * b];
    const int sx = src_loc[2 * b + 1];

    // receiver assignment hoisted out of the time loop
    bool rec_ok = false;
    int rec_idx = 0;
    if (tid < NREC_) {
        int rz = rec_loc[2 * tid];
        int rx = rec_loc[2 * tid + 1];
        if (rz >= z0 && rz < z0 + ROWS) {
            rec_ok = true;
            rec_idx = (rz - zv0) * NX_ + rx;
        }
    }

    // ---- stage-in (float4): stress(t0-1) then vel(t0-1) halo regions ----
    if (tid < SROWS * NX4) {
        int dz = tid / NX4;
        int x4 = tid - dz * NX4;
        int z  = zs0 + dz;
        if (z >= 0 && z < NZ_) {
            int g = base + z * NX_ + x4 * 4;
            reinterpret_cast<f4*>(txxl)[tid] = *reinterpret_cast<const f4*>(txxr + g);
            reinterpret_cast<f4*>(tzzl)[tid] = *reinterpret_cast<const f4*>(tzzr + g);
            reinterpret_cast<f4*>(txzl)[tid] = *reinterpret_cast<const f4*>(txzr + g);
        }
    }
    if (tid < VROWS * NX4) {
        int dz = tid / NX4;
        int x4 = tid - dz * NX4;
        int z  = zv0 + dz;
        if (z >= 0 && z < NZ_) {
            int g = base + z * NX_ + x4 * 4;
            reinterpret_cast<f4*>(vxl)[tid] = *reinterpret_cast<const f4*>(vxr + g);
            reinterpret_cast<f4*>(vzl)[tid] = *reinterpret_cast<const f4*>(vzr + g);
        }
    }
    __syncthreads();

    substep<0>(tid, z0, base, zv0, zs0, sz, sx, b, t0, vxl, vzl, txxl, tzzl, txzl,
               lam, dtmu, l2m, buoy, wav, rec_ok, rec_idx, out, vxw, vzw, txxw, tzzw, txzw);
    substep<1>(tid, z0, base, zv0, zs0, sz, sx, b, t0, vxl, vzl, txxl, tzzl, txzl,
               lam, dtmu, l2m, buoy, wav, rec_ok, rec_idx, out, vxw, vzw, txxw, tzzw, txzw);
    substep<2>(tid, z0, base, zv0, zs0, sz, sx, b, t0, vxl, vzl, txxl, tzzl, txzl,
               lam, dtmu, l2m, buoy, wav, rec_ok, rec_idx, out, vxw, vzw, txxw, tzzw, txzw);
    substep<3>(tid, z0, base, zv0, zs0, sz, sx, b, t0, vxl, vzl, txxl, tzzl, txzl,
               lam, dtmu, l2m, buoy, wav, rec_ok, rec_idx, out, vxw, vzw, txxw, tzzw, txzw);
}

extern "C" void kernel_launch(void* const* d_in, const int* in_sizes, int n_in,
                              void* d_out, int out_size, void* d_ws, size_t ws_size,
                              hipStream_t stream) {
    const float* xw      = (const float*)d_in[0];   // (B, NT, 1)
    const float* vp      = (const float*)d_in[1];   // (NZ, NX)
    const float* vs      = (const float*)d_in[2];
    const float* rho     = (const float*)d_in[3];
    const int*   src_loc = (const int*)d_in[4];     // (B, 2)
    const int*   rec_loc = (const int*)d_in[5];     // (NREC, 2)
    float*       out     = (float*)d_out;

    float* ws = (float*)d_ws;
    // double-buffered wavefields
    float* vx[2]  = { ws + 0 * N_FIELD, ws + 1 * N_FIELD };
    float* vz[2]  = { ws + 2 * N_FIELD, ws + 3 * N_FIELD };
    float* txx[2] = { ws + 4 * N_FIELD, ws + 5 * N_FIELD };
    float* tzz[2] = { ws + 6 * N_FIELD, ws + 7 * N_FIELD };
    float* txz[2] = { ws + 8 * N_FIELD, ws + 9 * N_FIELD };
    float* lam    = ws + 10 * N_FIELD;
    float* dtmu   = lam + N_CELL;
    float* l2m    = dtmu + N_CELL;
    float* buoy   = l2m + N_CELL;

    // zero all wavefield buffers
    hipMemsetAsync(d_ws, 0, (size_t)10 * N_FIELD * sizeof(float), stream);

    mat_kernel<<<(N_CELL + 255) / 256, 256, 0, stream>>>(vp, vs, rho, lam, dtmu, l2m, buoy);

    for (int L = 0; L < NT_ / K_; ++L) {
        int p = L & 1;
        step_kernel<<<NBLK, NTHR, LDS_BYTES, stream>>>(
            vx[p], vz[p], txx[p], tzz[p], txz[p],
            vx[1 - p], vz[1 - p], txx[1 - p], tzz[1 - p], txz[1 - p],
            lam, dtmu, l2m, buoy,
            xw, L * K_, src_loc, rec_loc, out);
    }
}

// Round 12
// 1153.882 us; speedup vs baseline: 1.0385x; 1.0385x over previous
//
#include <hip/hip_runtime.h>

// Match numpy's rounding exactly: no FMA contraction, same op order as reference.
#pragma clang fp contract(off)

#define B_    4
#define NT_   256
#define NZ_   192
#define NX_   192
#define NREC_ 128
#define DT_   0.001f
#define DH_   10.0f

#define N_CELL  (NZ_ * NX_)        // 36864
#define N_FIELD (B_ * N_CELL)      // 147456

#define K_     4                   // timesteps fused per launch
#define ROWS   3                   // rows owned per block
#define NTHR   1024                // threads per block (16 waves = 4/SIMD)
#define VH     (2 * K_ - 1)        // 7  vel halo rows each side
#define SH     (2 * K_)            // 8  stress halo rows each side
#define VROWS  (ROWS + 2 * VH)     // 17
#define SROWS  (ROWS + 2 * SH)     // 19
#define TILES  (NZ_ / ROWS)        // 64
#define NBLK   (B_ * TILES)        // 256  (one per CU)
#define NX4    (NX_ / 4)           // 48 float4 per row
#define LDS_BYTES ((2 * VROWS + 3 * SROWS) * NX_ * 4)   // 69888

using f4 = __attribute__((ext_vector_type(4))) float;

// ---------------- material precompute ----------------
__global__ void mat_kernel(const float* __restrict__ vp, const float* __restrict__ vs,
                           const float* __restrict__ rho,
                           float* __restrict__ lam, float* __restrict__ dtmu,
                           float* __restrict__ lam2mu, float* __restrict__ buoy) {
    int i = blockIdx.x * blockDim.x + threadIdx.x;
    if (i >= N_CELL) return;
    float vpi = vp[i], vsi = vs[i], rhoi = rho[i];
    float vs2 = vsi * vsi;
    float mui = rhoi * vs2;
    float lami = rhoi * (vpi * vpi - 2.0f * vs2);
    lam[i] = lami;
    dtmu[i] = DT_ * mui;             // reference: DT * mu * (...) == (DT*mu) * (...)
    lam2mu[i] = lami + 2.0f * mui;
    buoy[i] = DT_ * (1.0f / rhoi);   // see note below
    // NOTE: reference computes DT/rho directly; keep the exact same expression:
    buoy[i] = DT_ / rhoi;
}

// One fused substep. Fixed thread->cell mapping: own-cell fields in REGISTERS,
// LDS is only the halo-exchange medium. Per-element math identical to reference.
template<int S>
__device__ __forceinline__ void substep(
    bool zin, int z, int srow, int x4, int x0, int z0, int sz, int sx, int b, int t0,
    f4& r_vx, f4& r_vz, f4& r_txx, f4& r_tzz, f4& r_txz,
    const f4& m_bu, const f4& m_l, const f4& m_lm, const f4& m_dtm,
    float* __restrict__ vxl, float* __restrict__ vzl,
    float* __restrict__ txxl, float* __restrict__ tzzl, float* __restrict__ txzl,
    const float* __restrict__ wav,
    bool rec_ok, int rec_idx, int tid, float* __restrict__ out,
    int base, float* __restrict__ vxw, float* __restrict__ vzw,
    float* __restrict__ txxw, float* __restrict__ tzzw, float* __restrict__ txzw) {
    const int t = t0 + S;
    const int sOff = srow * NX_ + x0;          // own offset in stress LDS arrays
    const int vOff = (srow - 1) * NX_ + x0;    // own offset in vel LDS arrays (srow>=1)

    // ---- velocity update on rows [z0-hv, z0+ROWS-1+hv] ----
    {
        constexpr int hv = 2 * (K_ - 1 - S) + 1;
        bool act = zin && (z >= z0 - hv) && (z <= z0 + ROWS - 1 + hv);  // implies srow in [1,17]
        if (act) {
            f4 txn  = *reinterpret_cast<const f4*>(txxl + sOff + (x4 < NX4 - 1 ? 4 : 0));
            f4 tzp  = *reinterpret_cast<const f4*>(txzl + sOff - (x4 > 0 ? 4 : 0));
            f4 tzm  = *reinterpret_cast<const f4*>(txzl + sOff - NX_);
            f4 tzzp = *reinterpret_cast<const f4*>(tzzl + sOff + NX_);
#pragma unroll
            for (int e = 0; e < 4; ++e) {
                int xg = x0 + e;
                float txx_c = r_txx[e];
                float txxp1 = (e == 3) ? txn[0] : r_txx[e + 1];
                float txz_c = r_txz[e];
                float txzm1 = (e == 0) ? tzp[3] : r_txz[e - 1];
                float dxf_txx = (xg < NX_ - 1) ? (txxp1 - txx_c) / DH_ : 0.0f;
                float dzb_txz = (z >= 1)       ? (txz_c - tzm[e]) / DH_ : 0.0f;
                float dxb_txz = (xg >= 1)      ? (txz_c - txzm1) / DH_ : 0.0f;
                float dzf_tzz = (z < NZ_ - 1)  ? (tzzp[e] - r_tzz[e]) / DH_ : 0.0f;
                r_vx[e] = r_vx[e] + m_bu[e] * (dxf_txx + dzb_txz);
                r_vz[e] = r_vz[e] + m_bu[e] * (dxb_txz + dzf_tzz);
            }
            *reinterpret_cast<f4*>(vxl + vOff) = r_vx;
            *reinterpret_cast<f4*>(vzl + vOff) = r_vz;
            if (S == K_ - 1) {
                if (z >= z0 && z < z0 + ROWS) {
                    *reinterpret_cast<f4*>(vxw + base + z * NX_ + x0) = r_vx;
                    *reinterpret_cast<f4*>(vzw + base + z * NX_ + x0) = r_vz;
                }
            }
        }
    }
    __syncthreads();

    // ---- receiver recording (post-velocity snapshot), owner tile only ----
    // out layout: (NT, NREC, 2B) — out[t, r, b]=vx, out[t, r, B+b]=vz
    if (rec_ok) {
        size_t o = ((size_t)t * NREC_ + tid) * (2 * B_);
        out[o + b]      = vxl[rec_idx];
        out[o + B_ + b] = vzl[rec_idx];
    }

    // ---- stress update on rows [z0-hs, z0+ROWS-1+hs] ----
    {
        constexpr int hs = 2 * (K_ - 1 - S);
        bool act = zin && (z >= z0 - hs) && (z <= z0 + ROWS - 1 + hs);  // implies srow in [2,16]
        if (act) {
            f4 vxp  = *reinterpret_cast<const f4*>(vxl + vOff - (x4 > 0 ? 4 : 0));
            f4 vxzp = *reinterpret_cast<const f4*>(vxl + vOff + NX_);
            f4 vzn  = *reinterpret_cast<const f4*>(vzl + vOff + (x4 < NX4 - 1 ? 4 : 0));
            f4 vzm  = *reinterpret_cast<const f4*>(vzl + vOff - NX_);
            float w = wav[b * NT_ + t];
#pragma unroll
            for (int e = 0; e < 4; ++e) {
                int xg = x0 + e;
                float vx_c = r_vx[e];
                float vz_c = r_vz[e];
                float vxm1 = (e == 0) ? vxp[3] : r_vx[e - 1];
                float vzp1 = (e == 3) ? vzn[0] : r_vz[e + 1];
                float dvxdx  = (xg >= 1)      ? (vx_c - vxm1) / DH_ : 0.0f;
                float dvzdz  = (z >= 1)       ? (vz_c - vzm[e]) / DH_ : 0.0f;
                float dzf_vx = (z < NZ_ - 1)  ? (vxzp[e] - vx_c) / DH_ : 0.0f;
                float dxf_vz = (xg < NX_ - 1) ? (vzp1 - vz_c) / DH_ : 0.0f;
                float a  = r_txx[e] + DT_ * (m_lm[e] * dvxdx + m_l[e] * dvzdz);
                float bb = r_tzz[e] + DT_ * (m_l[e] * dvxdx + m_lm[e] * dvzdz);
                float cc = r_txz[e] + m_dtm[e] * (dzf_vx + dxf_vz);
                // source injection wherever the recompute range covers it (bit-identical
                // across owner and halo-recomputing blocks)
                if (z == sz && xg == sx) { a = a + w; bb = bb + w; }
                r_txx[e] = a; r_tzz[e] = bb; r_txz[e] = cc;
            }
            *reinterpret_cast<f4*>(txxl + sOff) = r_txx;
            *reinterpret_cast<f4*>(tzzl + sOff) = r_tzz;
            *reinterpret_cast<f4*>(txzl + sOff) = r_txz;
            if (S == K_ - 1) {   // stress range at last substep == owned rows
                int g = base + z * NX_ + x0;
                *reinterpret_cast<f4*>(txxw + g) = r_txx;
                *reinterpret_cast<f4*>(tzzw + g) = r_tzz;
                *reinterpret_cast<f4*>(txzw + g) = r_txz;
            }
        }
    }
    __syncthreads();
}

// ---------------- K_ fused timesteps, trapezoidal halo recompute, reg-resident ----
__global__ void __launch_bounds__(NTHR, 4)
step_kernel(const float* __restrict__ vxr, const float* __restrict__ vzr,
            const float* __restrict__ txxr, const float* __restrict__ tzzr,
            const float* __restrict__ txzr,
            float* __restrict__ vxw, float* __restrict__ vzw,
            float* __restrict__ txxw, float* __restrict__ tzzw, float* __restrict__ txzw,
            const float* __restrict__ lam, const float* __restrict__ dtmu,
            const float* __restrict__ l2m, const float* __restrict__ buoy,
            const float* __restrict__ wav, int t0,
            const int* __restrict__ src_loc, const int* __restrict__ rec_loc,
            float* __restrict__ out) {
    extern __shared__ float smem[];
    float* __restrict__ vxl  = smem;                          // [VROWS][NX_]
    float* __restrict__ vzl  = vxl  + VROWS * NX_;
    float* __restrict__ txxl = vzl  + VROWS * NX_;            // [SROWS][NX_]
    float* __restrict__ tzzl = txxl + SROWS * NX_;
    float* __restrict__ txzl = tzzl + SROWS * NX_;

    const int tid  = threadIdx.x;
    const int b    = blockIdx.x / TILES;
    const int tile = blockIdx.x % TILES;
    const int z0   = tile * ROWS;
    const int base = b * N_CELL;
    const int zv0  = z0 - VH;       // absolute z of vel LDS row 0
    const int zs0  = z0 - SH;       // absolute z of stress LDS row 0

    const int sz = src_loc[2 * b];
    const int sx = src_loc[2 * b + 1];

    // fixed mapping: thread -> (stress row, x-quad)
    const int srow = tid / NX4;                // 0..21 (>=SROWS -> idle)
    const int x4   = tid - srow * NX4;
    const int x0   = x4 * 4;
    const int z    = zs0 + srow;
    const bool zin = (srow < SROWS) && (z >= 0) && (z < NZ_);
    const bool vin = zin && srow >= 1 && srow <= VROWS;   // has a vel cell

    // receiver assignment hoisted out of the time loop
    bool rec_ok = false;
    int rec_idx = 0;
    if (tid < NREC_) {
        int rz = rec_loc[2 * tid];
        int rx = rec_loc[2 * tid + 1];
        if (rz >= z0 && rz < z0 + ROWS) {
            rec_ok = true;
            rec_idx = (rz - zv0) * NX_ + rx;
        }
    }

    // ---- stage-in to registers + LDS; materials to registers (once) ----
    f4 r_vx = {0,0,0,0}, r_vz = {0,0,0,0}, r_txx = {0,0,0,0}, r_tzz = {0,0,0,0}, r_txz = {0,0,0,0};
    f4 m_bu = {0,0,0,0}, m_l = {0,0,0,0}, m_lm = {0,0,0,0}, m_dtm = {0,0,0,0};
    if (zin) {
        int g = base + z * NX_ + x0;
        int c = z * NX_ + x0;
        r_txx = *reinterpret_cast<const f4*>(txxr + g);
        r_tzz = *reinterpret_cast<const f4*>(tzzr + g);
        r_txz = *reinterpret_cast<const f4*>(txzr + g);
        m_bu  = *reinterpret_cast<const f4*>(buoy + c);
        m_l   = *reinterpret_cast<const f4*>(lam  + c);
        m_lm  = *reinterpret_cast<const f4*>(l2m  + c);
        m_dtm = *reinterpret_cast<const f4*>(dtmu + c);
        int sOff = srow * NX_ + x0;
        *reinterpret_cast<f4*>(txxl + sOff) = r_txx;
        *reinterpret_cast<f4*>(tzzl + sOff) = r_tzz;
        *reinterpret_cast<f4*>(txzl + sOff) = r_txz;
        if (vin) {
            r_vx = *reinterpret_cast<const f4*>(vxr + g);
            r_vz = *reinterpret_cast<const f4*>(vzr + g);
            int vOff = (srow - 1) * NX_ + x0;
            *reinterpret_cast<f4*>(vxl + vOff) = r_vx;
            *reinterpret_cast<f4*>(vzl + vOff) = r_vz;
        }
    }
    __syncthreads();

    substep<0>(zin, z, srow, x4, x0, z0, sz, sx, b, t0, r_vx, r_vz, r_txx, r_tzz, r_txz,
               m_bu, m_l, m_lm, m_dtm, vxl, vzl, txxl, tzzl, txzl,
               wav, rec_ok, rec_idx, tid, out, base, vxw, vzw, txxw, tzzw, txzw);
    substep<1>(zin, z, srow, x4, x0, z0, sz, sx, b, t0, r_vx, r_vz, r_txx, r_tzz, r_txz,
               m_bu, m_l, m_lm, m_dtm, vxl, vzl, txxl, tzzl, txzl,
               wav, rec_ok, rec_idx, tid, out, base, vxw, vzw, txxw, tzzw, txzw);
    substep<2>(zin, z, srow, x4, x0, z0, sz, sx, b, t0, r_vx, r_vz, r_txx, r_tzz, r_txz,
               m_bu, m_l, m_lm, m_dtm, vxl, vzl, txxl, tzzl, txzl,
               wav, rec_ok, rec_idx, tid, out, base, vxw, vzw, txxw, tzzw, txzw);
    substep<3>(zin, z, srow, x4, x0, z0, sz, sx, b, t0, r_vx, r_vz, r_txx, r_tzz, r_txz,
               m_bu, m_l, m_lm, m_dtm, vxl, vzl, txxl, tzzl, txzl,
               wav, rec_ok, rec_idx, tid, out, base, vxw, vzw, txxw, tzzw, txzw);
}

extern "C" void kernel_launch(void* const* d_in, const int* in_sizes, int n_in,
                              void* d_out, int out_size, void* d_ws, size_t ws_size,
                              hipStream_t stream) {
    const float* xw      = (const float*)d_in[0];   // (B, NT, 1)
    const float* vp      = (const float*)d_in[1];   // (NZ, NX)
    const float* vs      = (const float*)d_in[2];
    const float* rho     = (const float*)d_in[3];
    const int*   src_loc = (const int*)d_in[4];     // (B, 2)
    const int*   rec_loc = (const int*)d_in[5];     // (NREC, 2)
    float*       out     = (float*)d_out;

    float* ws = (float*)d_ws;
    // double-buffered wavefields
    float* vx[2]  = { ws + 0 * N_FIELD, ws + 1 * N_FIELD };
    float* vz[2]  = { ws + 2 * N_FIELD, ws + 3 * N_FIELD };
    float* txx[2] = { ws + 4 * N_FIELD, ws + 5 * N_FIELD };
    float* tzz[2] = { ws + 6 * N_FIELD, ws + 7 * N_FIELD };
    float* txz[2] = { ws + 8 * N_FIELD, ws + 9 * N_FIELD };
    float* lam    = ws + 10 * N_FIELD;
    float* dtmu   = lam + N_CELL;
    float* l2m    = dtmu + N_CELL;
    float* buoy   = l2m + N_CELL;

    // zero all wavefield buffers
    hipMemsetAsync(d_ws, 0, (size_t)10 * N_FIELD * sizeof(float), stream);

    mat_kernel<<<(N_CELL + 255) / 256, 256, 0, stream>>>(vp, vs, rho, lam, dtmu, l2m, buoy);

    for (int L = 0; L < NT_ / K_; ++L) {
        int p = L & 1;
        step_kernel<<<NBLK, NTHR, LDS_BYTES, stream>>>(
            vx[p], vz[p], txx[p], tzz[p], txz[p],
            vx[1 - p], vz[1 - p], txx[1 - p], tzz[1 - p], txz[1 - p],
            lam, dtmu, l2m, buoy,
            xw, L * K_, src_loc, rec_loc, out);
    }
}